// Round 1
// baseline (32.219 us; speedup 1.0000x reference)
//
#include <hip/hip_runtime.h>
#include <hip/hip_bf16.h>

#define N_CENTERS 16

// Forward value of the soft-quantizer with straight-through estimator is
// numerically W_hard = center[argmin_m |x - center[m]|] (w_bias + W_soft
// cancels W_soft up to 1 ulp). Tie-break: np.argmin takes the FIRST index of
// the minimum -> strict '<' while scanning m ascending reproduces it exactly,
// since our per-element fp32 ops (sub, fabsf) are bit-identical to numpy's.
__global__ void __launch_bounds__(256) quantizer_kernel(
    const float* __restrict__ x,
    const float* __restrict__ center,
    float* __restrict__ out,
    int n4)
{
    // Broadcast the 16 centers into registers (wave-uniform loads, L2-hot).
    float c[N_CENTERS];
#pragma unroll
    for (int m = 0; m < N_CENTERS; ++m) c[m] = center[m];

    const float4* __restrict__ x4 = reinterpret_cast<const float4*>(x);
    float4* __restrict__ o4 = reinterpret_cast<float4*>(out);

    int tid = blockIdx.x * blockDim.x + threadIdx.x;
    int stride = gridDim.x * blockDim.x;

    for (int i = tid; i < n4; i += stride) {
        float4 v = x4[i];
        float xs[4] = {v.x, v.y, v.z, v.w};
        float r[4];
#pragma unroll
        for (int j = 0; j < 4; ++j) {
            float xv = xs[j];
            float best = fabsf(xv - c[0]);
            float bc = c[0];
#pragma unroll
            for (int m = 1; m < N_CENTERS; ++m) {
                float d = fabsf(xv - c[m]);
                bool lt = d < best;   // strict: first minimum wins (np.argmin)
                best = lt ? d : best;
                bc   = lt ? c[m] : bc;
            }
            r[j] = bc;
        }
        o4[i] = make_float4(r[0], r[1], r[2], r[3]);
    }
}

extern "C" void kernel_launch(void* const* d_in, const int* in_sizes, int n_in,
                              void* d_out, int out_size, void* d_ws, size_t ws_size,
                              hipStream_t stream) {
    const float* x      = (const float*)d_in[0];
    const float* center = (const float*)d_in[1];
    float* out          = (float*)d_out;

    int n = in_sizes[0];          // 16*64*128*128 = 16,777,216 (divisible by 4)
    int n4 = n / 4;

    const int block = 256;
    int grid = (n4 + block - 1) / block;
    if (grid > 2048) grid = 2048;  // grid-stride; ~8 blocks/CU on 256 CUs

    quantizer_kernel<<<grid, block, 0, stream>>>(x, center, out, n4);
}